// Round 1
// baseline (104.545 us; speedup 1.0000x reference)
//
#include <hip/hip_runtime.h>

// Static config (matches reference)
#define T_Q 8
#define H_Q 16
#define W_Q 16
#define HEADS 8
#define QDIM 64
#define QTOK (T_Q * H_Q * W_Q)   // 2048
#define KTOK 2048                 // T_K*H_K*W_K

// One block per query row. rel[0..15]=rel_h, rel[16..31]=rel_w, rel[32..39]=rel_t
__global__ __launch_bounds__(256)
void relpos_fused_kernel(const float* __restrict__ query,   // [B*H*QTOK, QDIM]
                         const float* __restrict__ scores,  // [B*H*QTOK, KTOK]
                         const float* __restrict__ hemb,    // [31, QDIM]
                         const float* __restrict__ wemb,    // [31, QDIM]
                         const float* __restrict__ temb,    // [15, QDIM]
                         float* __restrict__ out)           // [B*H*QTOK, KTOK]
{
    const int row  = blockIdx.x;            // (b*HEADS + n)*QTOK + qtok
    const int qtok = row & (QTOK - 1);
    const int t = (qtok >> 8) & 7;
    const int h = (qtok >> 4) & 15;
    const int w = qtok & 15;
    const int tid = threadIdx.x;

    __shared__ float q_s[QDIM];
    __shared__ float rel[40];

    if (tid < QDIM) q_s[tid] = query[(size_t)row * QDIM + tid];
    __syncthreads();

    if (tid < 40) {
        const float* emb;
        if (tid < 16) {
            emb = hemb + (size_t)(h - tid + 15) * QDIM;          // dist = h - hk + 15
        } else if (tid < 32) {
            emb = wemb + (size_t)(w - (tid - 16) + 15) * QDIM;   // dist = w - wk + 15
        } else {
            emb = temb + (size_t)(t - (tid - 32) + 7) * QDIM;    // dist = t - tk + 7
        }
        float acc = 0.f;
        #pragma unroll
        for (int c = 0; c < QDIM; c += 4) {
            float4 e = *reinterpret_cast<const float4*>(emb + c);
            acc += q_s[c]   * e.x;
            acc += q_s[c+1] * e.y;
            acc += q_s[c+2] * e.z;
            acc += q_s[c+3] * e.w;
        }
        rel[tid] = acc;
    }
    __syncthreads();

    const size_t base = (size_t)row * KTOK;
    // KTOK / (256 threads * 4 floats) = 2 iterations
    #pragma unroll
    for (int it = 0; it < 2; ++it) {
        const int k4 = (it * 256 + tid) * 4;       // 4-aligned; stays inside one hk group
        const int tk = k4 >> 8;
        const int hk = (k4 >> 4) & 15;
        const int wk = k4 & 15;
        const float add = rel[32 + tk] + rel[hk];
        float4 s = *reinterpret_cast<const float4*>(scores + base + k4);
        float4 o;
        o.x = s.x + add + rel[16 + wk + 0];
        o.y = s.y + add + rel[16 + wk + 1];
        o.z = s.z + add + rel[16 + wk + 2];
        o.w = s.w + add + rel[16 + wk + 3];
        *reinterpret_cast<float4*>(out + base + k4) = o;
    }
}

extern "C" void kernel_launch(void* const* d_in, const int* in_sizes, int n_in,
                              void* d_out, int out_size, void* d_ws, size_t ws_size,
                              hipStream_t stream) {
    const float* query  = (const float*)d_in[0];  // [2,8,2048,64]
    const float* scores = (const float*)d_in[1];  // [2,8,2048,2048]
    const float* hemb   = (const float*)d_in[2];  // [31,64]
    const float* wemb   = (const float*)d_in[3];  // [31,64]
    const float* temb   = (const float*)d_in[4];  // [15,64]
    float* out = (float*)d_out;

    const int B = in_sizes[0] / (HEADS * QTOK * QDIM);   // = 2
    const int rows = B * HEADS * QTOK;                    // 32768

    relpos_fused_kernel<<<rows, 256, 0, stream>>>(query, scores, hemb, wemb, temb, out);
}

// Round 2
// 100.519 us; speedup vs baseline: 1.0400x; 1.0400x over previous
//
#include <hip/hip_runtime.h>

// Static config (matches reference)
#define T_Q 8
#define H_Q 16
#define W_Q 16
#define HEADS 8
#define QDIM 64
#define QTOK (T_Q * H_Q * W_Q)   // 2048
#define KTOK 2048                 // T_K*H_K*W_K

typedef float f32x4 __attribute__((ext_vector_type(4)));

// 4 waves per block, one query row per wave. No serialized prologue:
// every wave computes its own 40 rel dot-products in parallel.
__global__ __launch_bounds__(256)
void relpos_fused_kernel(const float* __restrict__ query,   // [B*H*QTOK, QDIM]
                         const float* __restrict__ scores,  // [B*H*QTOK, KTOK]
                         const float* __restrict__ hemb,    // [31, QDIM]
                         const float* __restrict__ wemb,    // [31, QDIM]
                         const float* __restrict__ temb,    // [15, QDIM]
                         float* __restrict__ out)           // [B*H*QTOK, KTOK]
{
    const int tid  = threadIdx.x;
    const int wid  = tid >> 6;          // wave id 0..3
    const int lane = tid & 63;
    const int row  = blockIdx.x * 4 + wid;
    const int qtok = row & (QTOK - 1);
    const int t = (qtok >> 8) & 7;
    const int h = (qtok >> 4) & 15;
    const int w = qtok & 15;

    __shared__ float q_s[4][QDIM];
    __shared__ float rel[4][40];        // [0..15]=rel_h, [16..31]=rel_w, [32..39]=rel_t

    // Stage this wave's q row (coalesced 256B per wave, streamed once -> NT).
    q_s[wid][lane] = __builtin_nontemporal_load(query + (size_t)row * QDIM + lane);
    __syncthreads();

    // Lanes 0..39 of EACH wave compute that wave's 40 rel values.
    if (lane < 40) {
        const float* emb;
        if (lane < 16) {
            emb = hemb + (size_t)(h - lane + 15) * QDIM;          // dist = h - hk + 15
        } else if (lane < 32) {
            emb = wemb + (size_t)(w - (lane - 16) + 15) * QDIM;   // dist = w - wk + 15
        } else {
            emb = temb + (size_t)(t - (lane - 32) + 7) * QDIM;    // dist = t - tk + 7
        }
        float acc = 0.f;
        #pragma unroll
        for (int c = 0; c < QDIM; c += 4) {
            f32x4 e  = *reinterpret_cast<const f32x4*>(emb + c);
            f32x4 qv = *reinterpret_cast<const f32x4*>(&q_s[wid][c]);
            acc += qv.x * e.x + qv.y * e.y + qv.z * e.z + qv.w * e.w;
        }
        rel[wid][lane] = acc;
    }
    __syncthreads();

    // Hoist all rel lookups: per lane, hk = lane>>2 and wk = (lane&3)*4 are
    // loop-invariant; tk equals the iteration index.
    const float rh  = rel[wid][lane >> 2];
    const int   wk0 = (lane & 3) * 4;
    const float add0 = rh + rel[wid][16 + wk0 + 0];
    const float add1 = rh + rel[wid][16 + wk0 + 1];
    const float add2 = rh + rel[wid][16 + wk0 + 2];
    const float add3 = rh + rel[wid][16 + wk0 + 3];
    float rt[8];
    #pragma unroll
    for (int it = 0; it < 8; ++it) rt[it] = rel[wid][32 + it];

    // Stream the 2048-float row: 64 lanes x float4 x 8 iterations.
    const size_t base = (size_t)row * KTOK + lane * 4;
    #pragma unroll
    for (int it = 0; it < 8; ++it) {
        const f32x4 s = __builtin_nontemporal_load(
            reinterpret_cast<const f32x4*>(scores + base + it * 256));
        f32x4 o;
        o.x = s.x + add0 + rt[it];
        o.y = s.y + add1 + rt[it];
        o.z = s.z + add2 + rt[it];
        o.w = s.w + add3 + rt[it];
        __builtin_nontemporal_store(o,
            reinterpret_cast<f32x4*>(out + base + it * 256));
    }
}

extern "C" void kernel_launch(void* const* d_in, const int* in_sizes, int n_in,
                              void* d_out, int out_size, void* d_ws, size_t ws_size,
                              hipStream_t stream) {
    const float* query  = (const float*)d_in[0];  // [2,8,2048,64]
    const float* scores = (const float*)d_in[1];  // [2,8,2048,2048]
    const float* hemb   = (const float*)d_in[2];  // [31,64]
    const float* wemb   = (const float*)d_in[3];  // [31,64]
    const float* temb   = (const float*)d_in[4];  // [15,64]
    float* out = (float*)d_out;

    const int B = in_sizes[0] / (HEADS * QTOK * QDIM);   // = 2
    const int rows = B * HEADS * QTOK;                    // 32768

    relpos_fused_kernel<<<rows / 4, 256, 0, stream>>>(query, scores, hemb, wemb, temb, out);
}